// Round 2
// baseline (92.268 us; speedup 1.0000x reference)
//
#include <hip/hip_runtime.h>
#include <stdint.h>

#define Bb 8
#define Kc 256
#define NHALF 1024
#define Mtot 2048
#define NBLK_MMD (136 * Bb)

typedef short bf16x8 __attribute__((ext_vector_type(8)));
typedef float f32x4 __attribute__((ext_vector_type(4)));
typedef unsigned int u32x4 __attribute__((ext_vector_type(4)));

// ---- workspace layout (bytes) ----
#define OFF_ABF   0
#define OFF_SQ    (Bb*Mtot*Kc*2)              // Abf [B][M][K] bf16 = 8 MB
#define OFF_VROWP (OFF_SQ + Bb*Mtot*4)        // sq [B][M] f32
#define OFF_C     (OFF_VROWP + Bb*8*Kc*4)     // vrowp [B][8][K] f32
#define OFF_TOT   (OFF_C + 32)                // cc[5] f32 (padded)
#define OFF_CNT   (OFF_TOT + 8)               // total f64, then count u32

__device__ __forceinline__ unsigned short f2bf(float v) {
  unsigned u = __float_as_uint(v);
  unsigned r = u + 0x7FFFu + ((u >> 16) & 1u);   // RNE
  return (unsigned short)(r >> 16);
}
__device__ __forceinline__ float bf2f(unsigned short h) {
  return __uint_as_float(((unsigned)h) << 16);
}

// K1: transpose f32 [b][k][m] -> bf16 Abf [b][m][k]; sq[b][m] = sum_k xhat^2 (direct write).
// grid 256 = b(8) x mc(32); block 256 = m_off(64) x kq(4). Block 0 zeros total/count.
__global__ __launch_bounds__(256) void k_prep(const float* __restrict__ s,
                                              const float* __restrict__ t,
                                              unsigned short* __restrict__ Abf,
                                              float* __restrict__ sq,
                                              double* __restrict__ total,
                                              unsigned int* __restrict__ count) {
  if (blockIdx.x == 0 && threadIdx.x == 0) { *total = 0.0; *count = 0u; }
  const int b = blockIdx.x >> 5;
  const int mc = blockIdx.x & 31;
  const int l = threadIdx.x & 63;
  const int kq = threadIdx.x >> 6;
  const int m = mc * 64 + l;
  const float* __restrict__ p = (m < NHALF) ? (s + (size_t)b * Kc * NHALF + m)
                                            : (t + (size_t)b * Kc * NHALF + (m - NHALF));
  unsigned short* __restrict__ dst = Abf + ((size_t)b * Mtot + m) * Kc;
  float sqv = 0.f;
  const int kend = kq * 64 + 64;
  for (int k0 = kq * 64; k0 < kend; k0 += 8) {
    unsigned short h[8];
#pragma unroll
    for (int j = 0; j < 8; ++j) {
      float v = p[(size_t)(k0 + j) * NHALF];
      h[j] = f2bf(v);
      float hv = bf2f(h[j]);
      sqv = fmaf(hv, hv, sqv);
    }
    u32x4 v4;
    v4.x = (unsigned)h[0] | ((unsigned)h[1] << 16);
    v4.y = (unsigned)h[2] | ((unsigned)h[3] << 16);
    v4.z = (unsigned)h[4] | ((unsigned)h[5] << 16);
    v4.w = (unsigned)h[6] | ((unsigned)h[7] << 16);
    *(u32x4*)(dst + k0) = v4;
  }
  __shared__ float part[256];
  part[threadIdx.x] = sqv;
  __syncthreads();
  if (threadIdx.x < 64)
    sq[b * Mtot + mc * 64 + threadIdx.x] =
        part[threadIdx.x] + part[threadIdx.x + 64] + part[threadIdx.x + 128] + part[threadIdx.x + 192];
}

// K2: column-sum partials from bf16 Abf: vrowp[b][s][k] = sum_{m in slice s} Abf[b][m][k]
// grid 64 = b(8) x s(8); block 256 (one thread per k). Fully coalesced (lane = k).
__global__ __launch_bounds__(256) void k_colsum(const unsigned short* __restrict__ Abf,
                                                float* __restrict__ vrowp) {
  const int b = blockIdx.x >> 3;
  const int sl = blockIdx.x & 7;
  const int k = threadIdx.x;
  const unsigned short* __restrict__ base = Abf + ((size_t)b * Mtot + sl * 256) * Kc + k;
  float acc = 0.f;
#pragma unroll 8
  for (int mm = 0; mm < 256; ++mm) acc += bf2f(base[(size_t)mm * Kc]);
  vrowp[(b * 8 + sl) * Kc + k] = acc;
}

// K3: bandwidth via closed form: sumL2 = 2*M*S1 - 2*V2, V2 = sum_k colsum_k^2
__global__ __launch_bounds__(256) void k_bw(const float* __restrict__ sq,
                                            const float* __restrict__ vrowp,
                                            float* __restrict__ cc) {
  double s1 = 0.0, v2 = 0.0;
  for (int i = threadIdx.x; i < Bb * Mtot; i += 256) s1 += (double)sq[i];
  for (int i = threadIdx.x; i < Bb * Kc; i += 256) {
    const int b = i >> 8, k = i & 255;
    float cs = 0.f;
#pragma unroll
    for (int sl = 0; sl < 8; ++sl) cs += vrowp[(b * 8 + sl) * Kc + k];
    v2 += (double)cs * (double)cs;
  }
#pragma unroll
  for (int o = 32; o > 0; o >>= 1) { s1 += __shfl_down(s1, o); v2 += __shfl_down(v2, o); }
  __shared__ double rs[4], rv[4];
  if ((threadIdx.x & 63) == 0) { rs[threadIdx.x >> 6] = s1; rv[threadIdx.x >> 6] = v2; }
  __syncthreads();
  if (threadIdx.x == 0) {
    double S1 = rs[0] + rs[1] + rs[2] + rs[3];
    double V2 = rv[0] + rv[1] + rv[2] + rv[3];
    double sumL2 = 2.0 * (double)Mtot * S1 - 2.0 * V2;
    double bw = sumL2 / ((double)Mtot * (double)(Mtot - 1)) / 4.0;  // / KERNEL_MUL^(5//2)
#pragma unroll
    for (int i = 0; i < 5; ++i) cc[i] = (float)(1.0 / (bw * (double)(1 << i)));
  }
}

// K4: fused gram(X^T X) + L2 + 5-kernel exp sum + signed reduce + ticketed finalize.
__global__ __launch_bounds__(256) void k_mmd(const unsigned short* __restrict__ Abf,
                                             const float* __restrict__ sq,
                                             const float* __restrict__ cc,
                                             double* __restrict__ total,
                                             unsigned int* __restrict__ count,
                                             float* __restrict__ out) {
  __shared__ unsigned short As[128 * 32];
  __shared__ unsigned short Bs[128 * 32];
  __shared__ float red[4];

  const int b = blockIdx.y;
  int rem = blockIdx.x;                 // 0..135 triangular index
  int mi = 0;
  while (rem >= 16 - mi) { rem -= 16 - mi; ++mi; }
  const int mj = mi + rem;

  const int tid = threadIdx.x;
  const int lane = tid & 63;
  const int wid = tid >> 6;             // 4 waves, 2x2 wave grid, 64x64 each
  const int wr = wid >> 1, wc = wid & 1;
  const int l15 = lane & 15;
  const int k8 = lane >> 4;
  const int r0 = tid >> 2;              // staging row (pass 0)
  const int slot = tid & 3;             // 16B slot within 64B row

  const size_t boff = (size_t)b * Mtot * Kc;

  f32x4 acc[4][4];
  const f32x4 zero = {0.f, 0.f, 0.f, 0.f};
#pragma unroll
  for (int i = 0; i < 4; ++i)
#pragma unroll
    for (int j = 0; j < 4; ++j) acc[i][j] = zero;

  for (int kt = 0; kt < 8; ++kt) {
    const int kbase = kt * 32;
    // stage 2 tiles of [128 rows][32 k] bf16, LDS linear dest, XOR-swizzled SOURCE
#pragma unroll
    for (int pass = 0; pass < 2; ++pass) {
      const int r = r0 + pass * 64;
      const int sg = slot ^ ((r >> 1) & 3);
      const unsigned short* gA = Abf + boff + (size_t)(mi * 128 + r) * Kc + kbase + sg * 8;
      const unsigned short* gB = Abf + boff + (size_t)(mj * 128 + r) * Kc + kbase + sg * 8;
      char* lA = (char*)As + pass * 4096 + tid * 16;
      char* lB = (char*)Bs + pass * 4096 + tid * 16;
      __builtin_amdgcn_global_load_lds(
          (const __attribute__((address_space(1))) unsigned int*)(uintptr_t)gA,
          (__attribute__((address_space(3))) unsigned int*)(uintptr_t)lA, 16, 0, 0);
      __builtin_amdgcn_global_load_lds(
          (const __attribute__((address_space(1))) unsigned int*)(uintptr_t)gB,
          (__attribute__((address_space(3))) unsigned int*)(uintptr_t)lB, 16, 0, 0);
    }
    __syncthreads();

    bf16x8 af[4], bfr[4];
#pragma unroll
    for (int si = 0; si < 4; ++si) {
      const int ra = wr * 64 + si * 16 + l15;
      af[si] = *(const bf16x8*)((const char*)As + ra * 64 + ((k8 ^ ((ra >> 1) & 3)) * 16));
      const int rb = wc * 64 + si * 16 + l15;
      bfr[si] = *(const bf16x8*)((const char*)Bs + rb * 64 + ((k8 ^ ((rb >> 1) & 3)) * 16));
    }
#pragma unroll
    for (int si = 0; si < 4; ++si)
#pragma unroll
      for (int sj = 0; sj < 4; ++sj)
        acc[si][sj] = __builtin_amdgcn_mfma_f32_16x16x32_bf16(af[si], bfr[sj], acc[si][sj], 0, 0, 0);
    __syncthreads();
  }

  // epilogue: L2 = sq[m]+sq[n]-2g ; ksum = sum_i exp(-L2 * c[i])
  const float c0 = cc[0], c1 = cc[1], c2 = cc[2], c3 = cc[3], c4 = cc[4];
  const float* sqb = sq + b * Mtot;
  const int mbase = mi * 128 + wr * 64;
  const int nbase = mj * 128 + wc * 64;
  float sqn[4];
#pragma unroll
  for (int sj = 0; sj < 4; ++sj) sqn[sj] = sqb[nbase + sj * 16 + l15];
  float lsum = 0.f;
#pragma unroll
  for (int si = 0; si < 4; ++si) {
#pragma unroll
    for (int rg = 0; rg < 4; ++rg) {
      const int m = mbase + si * 16 + (lane >> 4) * 4 + rg;   // C/D: row=(l>>4)*4+reg
      const float sqm = sqb[m];
#pragma unroll
      for (int sj = 0; sj < 4; ++sj) {
        const float g = acc[si][sj][rg];
        const float nl2 = fmaf(2.f, g, -sqm) - sqn[sj];       // -L2
        lsum += __expf(nl2 * c0) + __expf(nl2 * c1) + __expf(nl2 * c2)
              + __expf(nl2 * c3) + __expf(nl2 * c4);
      }
    }
  }
  // sign: +1 same quadrant (XX,YY), -1 cross (XY,YX); weight 2 for off-diag tiles
  const float wsgn = ((mi == mj) ? 1.f : 2.f) * (((mi < 8) == (mj < 8)) ? 1.f : -1.f);
  lsum *= wsgn;
#pragma unroll
  for (int o = 32; o > 0; o >>= 1) lsum += __shfl_down(lsum, o);
  if (lane == 0) red[wid] = lsum;
  __syncthreads();
  if (tid == 0) {
    double bs = (double)red[0] + (double)red[1] + (double)red[2] + (double)red[3];
    atomicAdd(total, bs);
    __threadfence();
    unsigned int old = atomicAdd(count, 1u);
    if (old == NBLK_MMD - 1) {
      __threadfence();
      double tv = atomicAdd(total, 0.0);   // coherent device-scope read
      out[0] = (float)(tv / ((double)Bb * (double)NHALF * (double)NHALF));
    }
  }
}

extern "C" void kernel_launch(void* const* d_in, const int* in_sizes, int n_in,
                              void* d_out, int out_size, void* d_ws, size_t ws_size,
                              hipStream_t stream) {
  const float* src = (const float*)d_in[0];
  const float* tgt = (const float*)d_in[1];
  char* ws = (char*)d_ws;
  unsigned short* Abf = (unsigned short*)(ws + OFF_ABF);
  float* sq    = (float*)(ws + OFF_SQ);
  float* vrowp = (float*)(ws + OFF_VROWP);
  float* cc    = (float*)(ws + OFF_C);
  double* total = (double*)(ws + OFF_TOT);
  unsigned int* count = (unsigned int*)(ws + OFF_CNT);
  float* out = (float*)d_out;

  k_prep<<<256, 256, 0, stream>>>(src, tgt, Abf, sq, total, count);
  k_colsum<<<64, 256, 0, stream>>>(Abf, vrowp);
  k_bw<<<1, 256, 0, stream>>>(sq, vrowp, cc);
  k_mmd<<<dim3(136, Bb), 256, 0, stream>>>(Abf, sq, cc, total, count, out);
}

// Round 3
// 89.074 us; speedup vs baseline: 1.0359x; 1.0359x over previous
//
#include <hip/hip_runtime.h>
#include <stdint.h>

#define Bb 8
#define Kc 256
#define NHALF 1024
#define Mtot 2048
#define NTRI 136
#define NBLK_MMD (NTRI * Bb)

typedef short bf16x8 __attribute__((ext_vector_type(8)));
typedef float f32x4 __attribute__((ext_vector_type(4)));
typedef unsigned int u32x4 __attribute__((ext_vector_type(4)));

// ---- workspace layout (bytes) ----
#define OFF_ABF   0
#define OFF_SQ    (Bb*Mtot*Kc*2)               // Abf [B][M][K] bf16 = 8 MB
#define OFF_VROWP (OFF_SQ + Bb*Mtot*4)         // sq [B][M] f32 (64 KB)
#define OFF_C     (OFF_VROWP + Bb*32*Kc*4)     // vrowp [B][32][K] f32 (256 KB)
#define OFF_TOT   (OFF_C + 32)                 // cc f32 (padded to 32B)
#define OFF_CNT   (OFF_TOT + 8)                // total f64, then count[2] u32

#define GLOAD(gptr, lptr) __builtin_amdgcn_global_load_lds( \
    (const __attribute__((address_space(1))) unsigned int*)(uintptr_t)(gptr), \
    (__attribute__((address_space(3))) unsigned int*)(uintptr_t)(lptr), 16, 0, 0)

__device__ __forceinline__ unsigned short f2bf(float v) {
  unsigned u = __float_as_uint(v);
  unsigned r = u + 0x7FFFu + ((u >> 16) & 1u);   // RNE
  return (unsigned short)(r >> 16);
}
__device__ __forceinline__ float bf2f(unsigned short h) {
  return __uint_as_float(((unsigned)h) << 16);
}

// K1: transpose f32 [b][k][m] -> bf16 Abf [b][m][k]; sq[b][m] = sum_k xhat^2.
// grid 256 = b(8) x mc(32); block 256 = m_off(64) x kq(4). Block 0 zeros total/counts.
__global__ __launch_bounds__(256) void k_prep(const float* __restrict__ s,
                                              const float* __restrict__ t,
                                              unsigned short* __restrict__ Abf,
                                              float* __restrict__ sq,
                                              double* __restrict__ total,
                                              unsigned int* __restrict__ count) {
  if (blockIdx.x == 0 && threadIdx.x == 0) { *total = 0.0; count[0] = 0u; count[1] = 0u; }
  const int b = blockIdx.x >> 5;
  const int mc = blockIdx.x & 31;
  const int l = threadIdx.x & 63;
  const int kq = threadIdx.x >> 6;
  const int m = mc * 64 + l;
  const float* __restrict__ p = (m < NHALF) ? (s + (size_t)b * Kc * NHALF + m)
                                            : (t + (size_t)b * Kc * NHALF + (m - NHALF));
  unsigned short* __restrict__ dst = Abf + ((size_t)b * Mtot + m) * Kc;
  float sqv = 0.f;
  const int kend = kq * 64 + 64;
  for (int k0 = kq * 64; k0 < kend; k0 += 8) {
    unsigned short h[8];
#pragma unroll
    for (int j = 0; j < 8; ++j) {
      float v = p[(size_t)(k0 + j) * NHALF];
      h[j] = f2bf(v);
      float hv = bf2f(h[j]);
      sqv = fmaf(hv, hv, sqv);
    }
    u32x4 v4;
    v4.x = (unsigned)h[0] | ((unsigned)h[1] << 16);
    v4.y = (unsigned)h[2] | ((unsigned)h[3] << 16);
    v4.z = (unsigned)h[4] | ((unsigned)h[5] << 16);
    v4.w = (unsigned)h[6] | ((unsigned)h[7] << 16);
    *(u32x4*)(dst + k0) = v4;
  }
  __shared__ float part[256];
  part[threadIdx.x] = sqv;
  __syncthreads();
  if (threadIdx.x < 64)
    sq[b * Mtot + mc * 64 + threadIdx.x] =
        part[threadIdx.x] + part[threadIdx.x + 64] + part[threadIdx.x + 128] + part[threadIdx.x + 192];
}

// K2: column-sum partials + ticketed bandwidth finalize.
// grid 256 = sl(32) x b(8) [b = blockIdx&7 for XCD-L2 locality]; block 256 = mr(8) x kg(32).
__global__ __launch_bounds__(256) void k_stats(const unsigned short* __restrict__ Abf,
                                               const float* __restrict__ sq,
                                               float* __restrict__ vrowp,
                                               float* __restrict__ cc,
                                               unsigned int* __restrict__ count) {
  const int b = blockIdx.x & 7;
  const int sl = blockIdx.x >> 3;       // 0..31 : rows sl*64 .. sl*64+63
  const int tid = threadIdx.x;
  const int mr = tid >> 5;              // 0..7
  const int kg = tid & 31;              // 0..31 : k = kg*8..kg*8+7
  float a[8];
#pragma unroll
  for (int e = 0; e < 8; ++e) a[e] = 0.f;
  const unsigned short* __restrict__ base =
      Abf + ((size_t)b * Mtot + sl * 64 + mr) * Kc + kg * 8;
#pragma unroll
  for (int j = 0; j < 8; ++j) {         // rows mr + 8*j
    u32x4 v = *(const u32x4*)(base + (size_t)j * 8 * Kc);
    a[0] += bf2f((unsigned short)(v.x & 0xffff)); a[1] += bf2f((unsigned short)(v.x >> 16));
    a[2] += bf2f((unsigned short)(v.y & 0xffff)); a[3] += bf2f((unsigned short)(v.y >> 16));
    a[4] += bf2f((unsigned short)(v.z & 0xffff)); a[5] += bf2f((unsigned short)(v.z >> 16));
    a[6] += bf2f((unsigned short)(v.w & 0xffff)); a[7] += bf2f((unsigned short)(v.w >> 16));
  }
  __shared__ float lds[8][256];
#pragma unroll
  for (int e = 0; e < 8; ++e) lds[mr][kg * 8 + e] = a[e];
  __syncthreads();
  if (1) {
    float col = 0.f;
#pragma unroll
    for (int r = 0; r < 8; ++r) col += lds[r][tid];
    vrowp[((size_t)b * 32 + sl) * Kc + tid] = col;
  }
  // ticket: last block computes bandwidth coefficient
  __threadfence();
  __shared__ unsigned int lastFlag;
  if (tid == 0) lastFlag = (atomicAdd(&count[1], 1u) == 255u) ? 1u : 0u;
  __syncthreads();
  if (!lastFlag) return;
  __threadfence();
  double s1 = 0.0, v2 = 0.0;
  for (int i = tid; i < Bb * Mtot; i += 256) s1 += (double)sq[i];
  for (int i = tid; i < Bb * Kc; i += 256) {
    const int bb = i >> 8, k = i & 255;
    float cs = 0.f;
#pragma unroll
    for (int s2 = 0; s2 < 32; ++s2) cs += vrowp[((size_t)bb * 32 + s2) * Kc + k];
    v2 += (double)cs * (double)cs;
  }
#pragma unroll
  for (int o = 32; o > 0; o >>= 1) { s1 += __shfl_down(s1, o); v2 += __shfl_down(v2, o); }
  __shared__ double rs[4], rv[4];
  if ((tid & 63) == 0) { rs[tid >> 6] = s1; rv[tid >> 6] = v2; }
  __syncthreads();
  if (tid == 0) {
    double S1 = rs[0] + rs[1] + rs[2] + rs[3];
    double V2 = rv[0] + rv[1] + rv[2] + rv[3];
    double sumL2 = 2.0 * (double)Mtot * S1 - 2.0 * V2;
    double bw = sumL2 / ((double)Mtot * (double)(Mtot - 1)) / 4.0;  // / KERNEL_MUL^(5//2)
    cc[0] = (float)(1.0 / (bw * 16.0));   // coefficient of the SMALLEST kernel (i=4)
  }
}

// K3: fused gram + L2 + exp-chain epilogue + signed reduce + ticketed finalize.
// grid 1088 linear: b = blockIdx&7 (XCD L2 residency), tri-tile = blockIdx>>3.
__global__ __launch_bounds__(256) void k_mmd(const unsigned short* __restrict__ Abf,
                                             const float* __restrict__ sq,
                                             const float* __restrict__ cc,
                                             double* __restrict__ total,
                                             unsigned int* __restrict__ count,
                                             float* __restrict__ out) {
  __shared__ unsigned short As[2][128 * 32];   // 2 x 8 KB
  __shared__ unsigned short Bs[2][128 * 32];
  __shared__ float red[4];

  const int b = blockIdx.x & 7;
  int rem = blockIdx.x >> 3;            // 0..135 triangular index
  int mi = 0;
  while (rem >= 16 - mi) { rem -= 16 - mi; ++mi; }
  const int mj = mi + rem;

  const int tid = threadIdx.x;
  const int lane = tid & 63;
  const int wid = tid >> 6;             // 4 waves, 2x2 wave grid, 64x64 each
  const int wr = wid >> 1, wc = wid & 1;
  const int l15 = lane & 15;
  const int k8 = lane >> 4;
  const int r0 = tid >> 2;              // staging row (pass 0); pass1 = r0+64
  const int slot = tid & 3;

  const size_t boff = (size_t)b * Mtot * Kc;
  const int sg = slot ^ ((r0 >> 1) & 3);            // source swizzle (same for both passes)
  const unsigned short* gA = Abf + boff + (size_t)(mi * 128 + r0) * Kc + sg * 8;
  const unsigned short* gB = Abf + boff + (size_t)(mj * 128 + r0) * Kc + sg * 8;
  const int xk = (k8 ^ ((l15 >> 1) & 3)) * 16;      // matching read swizzle

  f32x4 acc[4][4];
  const f32x4 zero = {0.f, 0.f, 0.f, 0.f};
#pragma unroll
  for (int i = 0; i < 4; ++i)
#pragma unroll
    for (int j = 0; j < 4; ++j) acc[i][j] = zero;

  // prologue: stage tile 0 into buffer 0 (4 loads outstanding)
  GLOAD(gA,           (char*)As + tid * 16);
  GLOAD(gA + 64 * Kc, (char*)As + 4096 + tid * 16);
  GLOAD(gB,           (char*)Bs + tid * 16);
  GLOAD(gB + 64 * Kc, (char*)Bs + 4096 + tid * 16);

#pragma unroll
  for (int kt = 0; kt < 8; ++kt) {
    if (kt < 7) {
      const int nb = (kt + 1) & 1;
      const int kb = (kt + 1) * 32;
      GLOAD(gA + kb,           (char*)As + nb * 8192 + tid * 16);
      GLOAD(gA + kb + 64 * Kc, (char*)As + nb * 8192 + 4096 + tid * 16);
      GLOAD(gB + kb,           (char*)Bs + nb * 8192 + tid * 16);
      GLOAD(gB + kb + 64 * Kc, (char*)Bs + nb * 8192 + 4096 + tid * 16);
      asm volatile("s_waitcnt vmcnt(4)" ::: "memory");   // current tile's 4 done
    } else {
      asm volatile("s_waitcnt vmcnt(0)" ::: "memory");
    }
    __builtin_amdgcn_s_barrier();

    const int cb = kt & 1;
    const char* baseA = (const char*)As + cb * 8192;
    const char* baseB = (const char*)Bs + cb * 8192;
    bf16x8 af[4], bfr[4];
#pragma unroll
    for (int si = 0; si < 4; ++si) {
      const int ra = wr * 64 + si * 16 + l15;
      af[si] = *(const bf16x8*)(baseA + ra * 64 + xk);
      const int rb = wc * 64 + si * 16 + l15;
      bfr[si] = *(const bf16x8*)(baseB + rb * 64 + xk);
    }
#pragma unroll
    for (int si = 0; si < 4; ++si)
#pragma unroll
      for (int sj = 0; sj < 4; ++sj)
        acc[si][sj] = __builtin_amdgcn_mfma_f32_16x16x32_bf16(af[si], bfr[sj], acc[si][sj], 0, 0, 0);
    __builtin_amdgcn_s_barrier();
  }

  // epilogue: -L2 = 2g - sqm - sqn ; kernel sum via E + E^2 + E^4 + E^8 + E^16,
  // E = exp(-L2 * c4), c4 = 1/(bw*16) (the 5 bandwidths are powers of 2).
  const float cE = cc[0];
  const float* sqb = sq + b * Mtot;
  const int mbase = mi * 128 + wr * 64;
  const int nbase = mj * 128 + wc * 64;
  float sqn[4];
#pragma unroll
  for (int sj = 0; sj < 4; ++sj) sqn[sj] = sqb[nbase + sj * 16 + l15];
  float lsum = 0.f;
#pragma unroll
  for (int si = 0; si < 4; ++si) {
#pragma unroll
    for (int rg = 0; rg < 4; ++rg) {
      const int m = mbase + si * 16 + (lane >> 4) * 4 + rg;   // C/D: row=(l>>4)*4+reg
      const float sqm = sqb[m];
#pragma unroll
      for (int sj = 0; sj < 4; ++sj) {
        const float g = acc[si][sj][rg];
        const float nl2 = fmaf(2.f, g, -sqm) - sqn[sj];       // -L2
        const float E  = __expf(nl2 * cE);
        const float E2 = E * E, E4 = E2 * E2, E8 = E4 * E4, E16 = E8 * E8;
        lsum += ((E + E2) + (E4 + E8)) + E16;
      }
    }
  }
  const float wsgn = ((mi == mj) ? 1.f : 2.f) * (((mi < 8) == (mj < 8)) ? 1.f : -1.f);
  lsum *= wsgn;
#pragma unroll
  for (int o = 32; o > 0; o >>= 1) lsum += __shfl_down(lsum, o);
  if (lane == 0) red[wid] = lsum;
  __syncthreads();
  if (tid == 0) {
    double bs = (double)red[0] + (double)red[1] + (double)red[2] + (double)red[3];
    atomicAdd(total, bs);
    __threadfence();
    unsigned int old = atomicAdd(&count[0], 1u);
    if (old == NBLK_MMD - 1) {
      __threadfence();
      double tv = atomicAdd(total, 0.0);   // coherent device-scope read
      out[0] = (float)(tv / ((double)Bb * (double)NHALF * (double)NHALF));
    }
  }
}

extern "C" void kernel_launch(void* const* d_in, const int* in_sizes, int n_in,
                              void* d_out, int out_size, void* d_ws, size_t ws_size,
                              hipStream_t stream) {
  const float* src = (const float*)d_in[0];
  const float* tgt = (const float*)d_in[1];
  char* ws = (char*)d_ws;
  unsigned short* Abf = (unsigned short*)(ws + OFF_ABF);
  float* sq    = (float*)(ws + OFF_SQ);
  float* vrowp = (float*)(ws + OFF_VROWP);
  float* cc    = (float*)(ws + OFF_C);
  double* total = (double*)(ws + OFF_TOT);
  unsigned int* count = (unsigned int*)(ws + OFF_CNT);
  float* out = (float*)d_out;

  k_prep<<<256, 256, 0, stream>>>(src, tgt, Abf, sq, total, count);
  k_stats<<<256, 256, 0, stream>>>(Abf, sq, vrowp, cc, count);
  k_mmd<<<NBLK_MMD, 256, 0, stream>>>(Abf, sq, cc, total, count, out);
}

// Round 4
// 46.559 us; speedup vs baseline: 1.9817x; 1.9131x over previous
//
#include <hip/hip_runtime.h>
#include <stdint.h>

#define Bb 8
#define Kc 256
#define NHALF 1024
#define Mtot 2048
#define NTRI 136
#define NBLK_MMD (NTRI * Bb)

typedef short bf16x8 __attribute__((ext_vector_type(8)));
typedef float f32x4 __attribute__((ext_vector_type(4)));
typedef unsigned int u32x4 __attribute__((ext_vector_type(4)));

// ---- workspace layout (bytes) ----
#define OFF_ABF   0
#define OFF_SQ    (Bb*Mtot*Kc*2)               // Abf [B][M][K] bf16 = 8 MB
#define OFF_VROW  (OFF_SQ + Bb*Mtot*4)         // sq [B][M] f32 (64 KB)
#define OFF_S1P   (OFF_VROW + Bb*Kc*4)         // vrow [B][K] f32 (8 KB)
#define OFF_C     (OFF_S1P + 256*4)            // s1p [256] f32
#define OFF_TOT   (OFF_C + 32)                 // cc f32 (padded)

#define GLOAD(gptr, lptr) __builtin_amdgcn_global_load_lds( \
    (const __attribute__((address_space(1))) unsigned int*)(uintptr_t)(gptr), \
    (__attribute__((address_space(3))) unsigned int*)(uintptr_t)(lptr), 16, 0, 0)

__device__ __forceinline__ unsigned short f2bf(float v) {
  unsigned u = __float_as_uint(v);
  unsigned r = u + 0x7FFFu + ((u >> 16) & 1u);   // RNE
  return (unsigned short)(r >> 16);
}
__device__ __forceinline__ float bf2f(unsigned short h) {
  return __uint_as_float(((unsigned)h) << 16);
}

// K1: transpose f32 [b][k][m] -> bf16 Abf [b][m][k]; sq[b][m] = sum_k xhat^2;
// s1p[block] = sum over block's 64 rows of sq. Block 0 zeros total.
__global__ __launch_bounds__(256) void k_prep(const float* __restrict__ s,
                                              const float* __restrict__ t,
                                              unsigned short* __restrict__ Abf,
                                              float* __restrict__ sq,
                                              float* __restrict__ s1p,
                                              double* __restrict__ total) {
  if (blockIdx.x == 0 && threadIdx.x == 0) { *total = 0.0; }
  const int b = blockIdx.x >> 5;
  const int mc = blockIdx.x & 31;
  const int l = threadIdx.x & 63;
  const int kq = threadIdx.x >> 6;
  const int m = mc * 64 + l;
  const float* __restrict__ p = (m < NHALF) ? (s + (size_t)b * Kc * NHALF + m)
                                            : (t + (size_t)b * Kc * NHALF + (m - NHALF));
  unsigned short* __restrict__ dst = Abf + ((size_t)b * Mtot + m) * Kc;
  float sqv = 0.f;
  const int kend = kq * 64 + 64;
  for (int k0 = kq * 64; k0 < kend; k0 += 8) {
    unsigned short h[8];
#pragma unroll
    for (int j = 0; j < 8; ++j) {
      float v = p[(size_t)(k0 + j) * NHALF];
      h[j] = f2bf(v);
      float hv = bf2f(h[j]);
      sqv = fmaf(hv, hv, sqv);
    }
    u32x4 v4;
    v4.x = (unsigned)h[0] | ((unsigned)h[1] << 16);
    v4.y = (unsigned)h[2] | ((unsigned)h[3] << 16);
    v4.z = (unsigned)h[4] | ((unsigned)h[5] << 16);
    v4.w = (unsigned)h[6] | ((unsigned)h[7] << 16);
    *(u32x4*)(dst + k0) = v4;
  }
  __shared__ float part[256];
  part[threadIdx.x] = sqv;
  __syncthreads();
  if (threadIdx.x < 64) {
    float rv = part[threadIdx.x] + part[threadIdx.x + 64] +
               part[threadIdx.x + 128] + part[threadIdx.x + 192];
    sq[b * Mtot + mc * 64 + threadIdx.x] = rv;
#pragma unroll
    for (int o = 32; o > 0; o >>= 1) rv += __shfl_down(rv, o);
    if (threadIdx.x == 0) s1p[blockIdx.x] = rv;
  }
}

// K2: vrow[b][k] = sum_m X[k][m] from contiguous f32 originals. grid 2048, float4.
__global__ __launch_bounds__(256) void k_rowsum(const float* __restrict__ s,
                                                const float* __restrict__ t,
                                                float* __restrict__ vrow) {
  const int bk = blockIdx.x;            // b*256 + k
  const f32x4* __restrict__ ps = (const f32x4*)(s + (size_t)bk * NHALF);
  const f32x4* __restrict__ pt = (const f32x4*)(t + (size_t)bk * NHALF);
  f32x4 a = ps[threadIdx.x];
  f32x4 c = pt[threadIdx.x];
  float acc = (a.x + a.y) + (a.z + a.w) + (c.x + c.y) + (c.z + c.w);
#pragma unroll
  for (int o = 32; o > 0; o >>= 1) acc += __shfl_down(acc, o);
  __shared__ float red[4];
  if ((threadIdx.x & 63) == 0) red[threadIdx.x >> 6] = acc;
  __syncthreads();
  if (threadIdx.x == 0) vrow[bk] = (red[0] + red[1]) + (red[2] + red[3]);
}

// K3: bandwidth coefficient from 9 KB of partials. cc[0] includes log2(e) for exp2f.
__global__ __launch_bounds__(256) void k_bw(const float* __restrict__ s1p,
                                            const float* __restrict__ vrow,
                                            float* __restrict__ cc) {
  double s1 = 0.0, v2 = 0.0;
  { double x = (double)s1p[threadIdx.x]; s1 = x; }
  for (int i = threadIdx.x; i < Bb * Kc; i += 256) { double x = (double)vrow[i]; v2 += x * x; }
#pragma unroll
  for (int o = 32; o > 0; o >>= 1) { s1 += __shfl_down(s1, o); v2 += __shfl_down(v2, o); }
  __shared__ double rs[4], rv[4];
  if ((threadIdx.x & 63) == 0) { rs[threadIdx.x >> 6] = s1; rv[threadIdx.x >> 6] = v2; }
  __syncthreads();
  if (threadIdx.x == 0) {
    double S1 = rs[0] + rs[1] + rs[2] + rs[3];
    double V2 = rv[0] + rv[1] + rv[2] + rv[3];
    double sumL2 = 2.0 * (double)Mtot * S1 - 2.0 * V2;
    double bw = sumL2 / ((double)Mtot * (double)(Mtot - 1)) / 4.0;  // / KERNEL_MUL^(5//2)
    // E = exp(-L2/(bw*16)) = exp2(-L2 * log2e/(bw*16))
    cc[0] = (float)(1.4426950408889634 / (bw * 16.0));
  }
}

// K4: fused gram + L2 + exp-chain epilogue + signed reduce. No fences, no tickets.
// grid 1088 linear: b = blockIdx&7 (XCD L2 residency), tri-tile = blockIdx>>3.
__global__ __launch_bounds__(256) void k_mmd(const unsigned short* __restrict__ Abf,
                                             const float* __restrict__ sq,
                                             const float* __restrict__ cc,
                                             double* __restrict__ total) {
  __shared__ unsigned short As[2][128 * 32];   // 2 x 8 KB
  __shared__ unsigned short Bs[2][128 * 32];
  __shared__ float red[4];

  const int b = blockIdx.x & 7;
  int rem = blockIdx.x >> 3;            // 0..135 triangular index
  int mi = 0;
  while (rem >= 16 - mi) { rem -= 16 - mi; ++mi; }
  const int mj = mi + rem;

  const int tid = threadIdx.x;
  const int lane = tid & 63;
  const int wid = tid >> 6;             // 4 waves, 2x2 wave grid, 64x64 each
  const int wr = wid >> 1, wc = wid & 1;
  const int l15 = lane & 15;
  const int k8 = lane >> 4;
  const int r0 = tid >> 2;              // staging row (pass 0); pass1 = r0+64
  const int slot = tid & 3;

  const size_t boff = (size_t)b * Mtot * Kc;
  const int sg = slot ^ ((r0 >> 1) & 3);            // source swizzle
  const unsigned short* gA = Abf + boff + (size_t)(mi * 128 + r0) * Kc + sg * 8;
  const unsigned short* gB = Abf + boff + (size_t)(mj * 128 + r0) * Kc + sg * 8;
  const int xk = (k8 ^ ((l15 >> 1) & 3)) * 16;      // matching read swizzle

  f32x4 acc[4][4];
  const f32x4 zero = {0.f, 0.f, 0.f, 0.f};
#pragma unroll
  for (int i = 0; i < 4; ++i)
#pragma unroll
    for (int j = 0; j < 4; ++j) acc[i][j] = zero;

  // prologue: stage tile 0 into buffer 0 (4 loads outstanding)
  GLOAD(gA,           (char*)As + tid * 16);
  GLOAD(gA + 64 * Kc, (char*)As + 4096 + tid * 16);
  GLOAD(gB,           (char*)Bs + tid * 16);
  GLOAD(gB + 64 * Kc, (char*)Bs + 4096 + tid * 16);

#pragma unroll
  for (int kt = 0; kt < 8; ++kt) {
    if (kt < 7) {
      const int nb = (kt + 1) & 1;
      const int kb = (kt + 1) * 32;
      GLOAD(gA + kb,           (char*)As + nb * 8192 + tid * 16);
      GLOAD(gA + kb + 64 * Kc, (char*)As + nb * 8192 + 4096 + tid * 16);
      GLOAD(gB + kb,           (char*)Bs + nb * 8192 + tid * 16);
      GLOAD(gB + kb + 64 * Kc, (char*)Bs + nb * 8192 + 4096 + tid * 16);
      asm volatile("s_waitcnt vmcnt(4)" ::: "memory");   // current tile's 4 done
    } else {
      asm volatile("s_waitcnt vmcnt(0)" ::: "memory");
    }
    __builtin_amdgcn_s_barrier();

    const int cb = kt & 1;
    const char* baseA = (const char*)As + cb * 8192;
    const char* baseB = (const char*)Bs + cb * 8192;
    bf16x8 af[4], bfr[4];
#pragma unroll
    for (int si = 0; si < 4; ++si) {
      const int ra = wr * 64 + si * 16 + l15;
      af[si] = *(const bf16x8*)(baseA + ra * 64 + xk);
      const int rb = wc * 64 + si * 16 + l15;
      bfr[si] = *(const bf16x8*)(baseB + rb * 64 + xk);
    }
#pragma unroll
    for (int si = 0; si < 4; ++si)
#pragma unroll
      for (int sj = 0; sj < 4; ++sj)
        acc[si][sj] = __builtin_amdgcn_mfma_f32_16x16x32_bf16(af[si], bfr[sj], acc[si][sj], 0, 0, 0);
    __builtin_amdgcn_s_barrier();
  }

  // epilogue: -L2 = 2g - sqm - sqn ; kernel sum = E + E^2 + E^4 + E^8 + E^16,
  // E = exp2(-L2 * cE), cE = log2e/(bw*16) (the 5 bandwidths are powers of 2).
  const float cE = cc[0];
  const float* sqb = sq + b * Mtot;
  const int mbase = mi * 128 + wr * 64;
  const int nbase = mj * 128 + wc * 64;
  float sqn[4];
#pragma unroll
  for (int sj = 0; sj < 4; ++sj) sqn[sj] = sqb[nbase + sj * 16 + l15];
  float lsum = 0.f;
#pragma unroll
  for (int si = 0; si < 4; ++si) {
#pragma unroll
    for (int rg = 0; rg < 4; ++rg) {
      const int m = mbase + si * 16 + (lane >> 4) * 4 + rg;   // C/D: row=(l>>4)*4+reg
      const float sqm = sqb[m];
#pragma unroll
      for (int sj = 0; sj < 4; ++sj) {
        const float g = acc[si][sj][rg];
        const float nl2 = fmaf(2.f, g, -sqm) - sqn[sj];       // -L2
        const float E  = exp2f(nl2 * cE);
        const float E2 = E * E, E4 = E2 * E2, E8 = E4 * E4, E16 = E8 * E8;
        lsum += ((E + E2) + (E4 + E8)) + E16;
      }
    }
  }
  const float wsgn = ((mi == mj) ? 1.f : 2.f) * (((mi < 8) == (mj < 8)) ? 1.f : -1.f);
  lsum *= wsgn;
#pragma unroll
  for (int o = 32; o > 0; o >>= 1) lsum += __shfl_down(lsum, o);
  if (lane == 0) red[wid] = lsum;
  __syncthreads();
  if (tid == 0) {
    double bs = (double)red[0] + (double)red[1] + (double)red[2] + (double)red[3];
    atomicAdd(total, bs);
  }
}

__global__ void k_final(const double* __restrict__ total, float* __restrict__ out) {
  out[0] = (float)(*total / ((double)Bb * (double)NHALF * (double)NHALF));
}

extern "C" void kernel_launch(void* const* d_in, const int* in_sizes, int n_in,
                              void* d_out, int out_size, void* d_ws, size_t ws_size,
                              hipStream_t stream) {
  const float* src = (const float*)d_in[0];
  const float* tgt = (const float*)d_in[1];
  char* ws = (char*)d_ws;
  unsigned short* Abf = (unsigned short*)(ws + OFF_ABF);
  float* sq   = (float*)(ws + OFF_SQ);
  float* vrow = (float*)(ws + OFF_VROW);
  float* s1p  = (float*)(ws + OFF_S1P);
  float* cc   = (float*)(ws + OFF_C);
  double* total = (double*)(ws + OFF_TOT);
  float* out = (float*)d_out;

  k_prep<<<256, 256, 0, stream>>>(src, tgt, Abf, sq, s1p, total);
  k_rowsum<<<Bb * Kc, 256, 0, stream>>>(src, tgt, vrow);
  k_bw<<<1, 256, 0, stream>>>(s1p, vrow, cc);
  k_mmd<<<NBLK_MMD, 256, 0, stream>>>(Abf, sq, cc, total);
  k_final<<<1, 1, 0, stream>>>(total, out);
}